// Round 11
// baseline (451.640 us; speedup 1.0000x reference)
//
#include <hip/hip_runtime.h>
#include <math.h>

#define NB   128
#define CF   1024
#define RR   256
#define NA   312
#define DV   300
#define MT   640
#define NKC  32
#define NQ   160
#define NPP  320          // pairs per b (padded)

typedef _Float16 half8  __attribute__((ext_vector_type(8)));
typedef _Float16 half4  __attribute__((ext_vector_type(4)));
typedef float float16v  __attribute__((ext_vector_type(16)));
typedef float float4v   __attribute__((ext_vector_type(4)));

// ---- K0: Q projection (pair-interleaved Qb rows: row 2i = Q1_i, 2i+1 = Q2_i) ----
__launch_bounds__(256, 4)
__global__ void k_q(const float* __restrict__ V, const float* __restrict__ W1,
                    const float* __restrict__ W2, _Float16* __restrict__ Qb) {
    int ib = blockIdx.x;
    int t  = threadIdx.x;
    bool isQ2 = ib >= 80;
    int i0l = (ib - (isQ2 ? 80 : 0)) * 4;
    __shared__ float inv4[4];
    float acc[4][4];
    #pragma unroll
    for (int ii = 0; ii < 4; ++ii)
        #pragma unroll
        for (int j = 0; j < 4; ++j) acc[ii][j] = 0.f;
    if (i0l < NA) {
        int row = t >> 6, l64 = t & 63;
        float s = 0.f;
        for (int v = l64; v < DV; v += 64) { float x = V[(i0l + row) * DV + v]; s += x * x; }
        #pragma unroll
        for (int o = 32; o; o >>= 1) s += __shfl_xor(s, o, 64);
        if (l64 == 0) inv4[row] = 1.f / fmaxf(sqrtf(s), 1e-12f);
        __syncthreads();
        const float* W  = isQ2 ? W2 : W1;
        const float* Vb = V + (size_t)i0l * DV;
        for (int v = 0; v < DV; v += 2) {
            float4v w0 = *(const float4v*)(W + (size_t)v * CF + t * 4);
            float4v w1 = *(const float4v*)(W + (size_t)(v + 1) * CF + t * 4);
            #pragma unroll
            for (int ii = 0; ii < 4; ++ii) {
                float a0 = Vb[(size_t)ii * DV + v];
                float a1 = Vb[(size_t)ii * DV + v + 1];
                #pragma unroll
                for (int j = 0; j < 4; ++j) acc[ii][j] += a0 * w0[j] + a1 * w1[j];
            }
        }
        #pragma unroll
        for (int ii = 0; ii < 4; ++ii)
            #pragma unroll
            for (int j = 0; j < 4; ++j) acc[ii][j] *= inv4[ii];
    }
    int fg = t >> 3;
    int fo = (t & 7) * 4;
    int q12 = isQ2 ? 1 : 0;
    #pragma unroll
    for (int ii = 0; ii < 4; ++ii) {
        half4 h;
        #pragma unroll
        for (int j = 0; j < 4; ++j) h[j] = (_Float16)acc[ii][j];
        *(half4*)&Qb[((size_t)fg * MT + (2 * (i0l + ii) + q12)) * 32 + fo] = h;
    }
}

// ---- K1: zero-sync fused GEMM+norm+partial-softmax.                      ----
// block = (b, rq, mh): M=320 x N=64, 4 waves, NO LDS / NO barriers in loop. ----
// Wave (wm,wn): acc[5] (80 AGPR); A,B loaded per-lane straight to registers. ----
__launch_bounds__(256, 3)
__global__ void k_fused(const float* __restrict__ img, const _Float16* __restrict__ Qb,
                        float* __restrict__ pm, float* __restrict__ ps,
                        float* __restrict__ pd) {
    int lin = blockIdx.x;          // 0..1023
    int b   = lin & 127;           // lin%8 = b%8 -> all 8 subblocks of b on one XCD
    int sub = lin >> 7;            // 0..7
    int rq  = sub & 3;             // r-quarter (64 cols)
    int mh  = sub >> 2;            // M-half (320 rows)

    int tid  = threadIdx.x;        // 0..255
    int lane = tid & 63;
    int w    = tid >> 6;           // 0..3
    int wm   = w >> 1;             // 0..1: rows [mh*320 + wm*160, +160)
    int wn   = w & 1;              // 0..1: cols [rq*64 + wn*32, +32)
    int nl   = lane & 31;
    int kh   = lane >> 5;

    // A per-lane base: Qb byte (row)*64 + kh*16; row = mh*320 + wm*160 + mt*32 + nl
    const char* gA = (const char*)Qb + (size_t)(mh * 320 + wm * 160 + nl) * 64 + kh * 16;
    // B per-lane: col = rq*64 + wn*32 + nl; f = kc*32 + kh*8 + ks*16 + j
    const float* gB = img + (size_t)b * CF * RR + (size_t)kh * 8 * RR
                      + rq * 64 + wn * 32 + nl;

    float16v acc[5];
    #pragma unroll
    for (int i = 0; i < 5; ++i)
        #pragma unroll
        for (int gi = 0; gi < 16; ++gi) acc[i][gi] = 0.f;
    float ssq = 0.f;               // this lane's column, its kh-half of f
    float Bv[16];
    half8 bf0, bf1;
    half8 Av[5][2];

    #define BLOAD(kc_) do {                                                        \
        int kcl = (kc_) < NKC ? (kc_) : (NKC - 1);                                 \
        const float* p = gB + (size_t)kcl * 32 * RR;                               \
        _Pragma("unroll")                                                          \
        for (int ks = 0; ks < 2; ++ks)                                             \
            _Pragma("unroll")                                                      \
            for (int j = 0; j < 8; ++j)                                            \
                Bv[ks * 8 + j] = p[(size_t)(ks * 16 + j) * RR];                    \
    } while (0)

    #define ALOAD(kc_) do {                                                        \
        int kcl = (kc_) < NKC ? (kc_) : (NKC - 1);                                 \
        const char* a = gA + (size_t)kcl * (MT * 64);                              \
        _Pragma("unroll")                                                          \
        for (int mt = 0; mt < 5; ++mt)                                             \
            _Pragma("unroll")                                                      \
            for (int ks = 0; ks < 2; ++ks)                                         \
                Av[mt][ks] = *(const half8*)(a + mt * 32 * 64 + ks * 32);          \
    } while (0)

    #define BCVT() do {                                                            \
        _Pragma("unroll")                                                          \
        for (int j = 0; j < 8; ++j) {                                              \
            float x0 = Bv[j], x1 = Bv[8 + j];                                      \
            ssq += x0 * x0; ssq += x1 * x1;                                        \
            bf0[j] = (_Float16)x0; bf1[j] = (_Float16)x1;                          \
        }                                                                          \
    } while (0)

    #define COMPUTE() do {                                                         \
        _Pragma("unroll")                                                          \
        for (int mt = 0; mt < 5; ++mt)                                             \
            acc[mt] = __builtin_amdgcn_mfma_f32_32x32x16_f16(Av[mt][0], bf0, acc[mt], 0, 0, 0); \
        _Pragma("unroll")                                                          \
        for (int mt = 0; mt < 5; ++mt)                                             \
            acc[mt] = __builtin_amdgcn_mfma_f32_32x32x16_f16(Av[mt][1], bf1, acc[mt], 0, 0, 0); \
    } while (0)

    BLOAD(0);
    ALOAD(0);
    #pragma unroll 1
    for (int kc = 0; kc < NKC; ++kc) {
        __builtin_amdgcn_sched_barrier(0);
        BCVT();                      // compiler waits Bv(kc) precisely
        BLOAD(kc + 1);               // prefetch next B (WAR on Bv resolved by BCVT)
        __builtin_amdgcn_sched_barrier(0);
        __builtin_amdgcn_s_setprio(1);
        COMPUTE();                   // compiler waits Av(kc) precisely
        __builtin_amdgcn_s_setprio(0);
        __builtin_amdgcn_sched_barrier(0);
        ALOAD(kc + 1);               // prefetch next A (WAR on Av resolved by COMPUTE)
    }
    #undef BLOAD
    #undef ALOAD
    #undef BCVT
    #undef COMPUTE

    // ---- epilogue: norm scale, partial softmax over this block's 64 r ----
    __shared__ float mred[2][160];
    __shared__ float mg[160];
    __shared__ float sred[2][160];
    __shared__ float dred[2][160];

    ssq += __shfl_xor(ssq, 32, 64);          // merge kh halves -> full column sumsq
    float iv = 1.f / fmaxf(sqrtf(ssq), 1e-12f);
    #pragma unroll
    for (int mt = 0; mt < 5; ++mt)
        #pragma unroll
        for (int gi = 0; gi < 16; ++gi) acc[mt][gi] *= iv;

    // pass 1: per-pair max over 32 cols (this wave's wn group)
    #pragma unroll
    for (int mt = 0; mt < 5; ++mt) {
        #pragma unroll
        for (int e = 0; e < 8; ++e) {
            int g = 2 * e;
            float mx = acc[mt][g];
            #pragma unroll
            for (int off = 1; off <= 16; off <<= 1)
                mx = fmaxf(mx, __shfl_xor(mx, off, 64));
            if (nl == 0) {
                int row = (g & 3) + 8 * (g >> 2) + 4 * kh;     // even, 0..30
                mred[wn][wm * 80 + mt * 16 + (row >> 1)] = mx;
            }
        }
    }
    __syncthreads();
    if (tid < 160) mg[tid] = fmaxf(mred[0][tid], mred[1][tid]);
    __syncthreads();

    // pass 2: exp-sum and weighted Q2 dot (local max)
    #pragma unroll
    for (int mt = 0; mt < 5; ++mt) {
        #pragma unroll
        for (int e = 0; e < 8; ++e) {
            int g = 2 * e;
            int row = (g & 3) + 8 * (g >> 2) + 4 * kh;
            int i   = wm * 80 + mt * 16 + (row >> 1);
            float m  = mg[i];
            float e0 = __expf(acc[mt][g] - m);
            float s = e0;
            float d = e0 * acc[mt][g + 1];
            #pragma unroll
            for (int off = 1; off <= 16; off <<= 1) {
                s += __shfl_xor(s, off, 64);
                d += __shfl_xor(d, off, 64);
            }
            if (nl == 0) {
                sred[wn][i] = s;
                dred[wn][i] = d;
            }
        }
    }
    __syncthreads();
    if (tid < 160) {
        size_t pb = ((size_t)b * 4 + rq) * NPP + mh * 160 + tid;
        pm[pb] = mg[tid];
        ps[pb] = sred[0][tid] + sred[1][tid];
        pd[pb] = dred[0][tid] + dred[1][tid];
    }
}

// ---- K2: combine the four r-quarters (flash-style) ----
__launch_bounds__(256, 4)
__global__ void k_comb(const float* __restrict__ pm, const float* __restrict__ ps,
                       const float* __restrict__ pd, float* __restrict__ out) {
    int idx = blockIdx.x * 256 + threadIdx.x;   // 0..40959 = 128*320
    int b = idx / NPP;
    int i = idx - b * NPP;
    size_t base = (size_t)b * 4 * NPP + i;
    float m0 = pm[base], m1 = pm[base + NPP], m2 = pm[base + 2 * NPP], m3 = pm[base + 3 * NPP];
    float m  = fmaxf(fmaxf(m0, m1), fmaxf(m2, m3));
    float w0 = __expf(m0 - m), w1 = __expf(m1 - m);
    float w2 = __expf(m2 - m), w3 = __expf(m3 - m);
    float s = ps[base] * w0 + ps[base + NPP] * w1 + ps[base + 2 * NPP] * w2 + ps[base + 3 * NPP] * w3;
    float d = pd[base] * w0 + pd[base + NPP] * w1 + pd[base + 2 * NPP] * w2 + pd[base + 3 * NPP] * w3;
    if (i < NA) out[(size_t)b * NA + i] = d / s;
}

// ---- launcher ----
extern "C" void kernel_launch(void* const* d_in, const int* in_sizes, int n_in,
                              void* d_out, int out_size, void* d_ws, size_t ws_size,
                              hipStream_t stream) {
    const float* img = (const float*)d_in[0];
    const float* V   = (const float*)d_in[1];
    const float* W1  = (const float*)d_in[2];
    const float* W2  = (const float*)d_in[3];
    float* out = (float*)d_out;

    char* ws = (char*)d_ws;
    size_t off = 0;
    _Float16* Qb = (_Float16*)(ws + off); off += (size_t)NKC * MT * 32 * 2;
    float*    pm = (float*)(ws + off);    off += (size_t)NB * 4 * NPP * 4;
    float*    ps = (float*)(ws + off);    off += (size_t)NB * 4 * NPP * 4;
    float*    pd = (float*)(ws + off);    off += (size_t)NB * 4 * NPP * 4;

    k_q<<<dim3(NQ), 256, 0, stream>>>(V, W1, W2, Qb);
    k_fused<<<dim3(1024), 256, 0, stream>>>(img, Qb, pm, ps, pd);
    k_comb<<<dim3(160), 256, 0, stream>>>(pm, ps, pd, out);
}

// Round 12
// 284.417 us; speedup vs baseline: 1.5879x; 1.5879x over previous
//
#include <hip/hip_runtime.h>
#include <math.h>

#define NB   128
#define CF   1024
#define RR   256
#define NA   312
#define DV   300
#define MT   640
#define NKC  32
#define NQ   160
#define NPI  320          // pairs per (b, nh) output group (padded)
#define BUFSZ 16384       // A 8 KB + B 8 KB per buffer

typedef _Float16 half8  __attribute__((ext_vector_type(8)));
typedef _Float16 half4  __attribute__((ext_vector_type(4)));
typedef float float16v  __attribute__((ext_vector_type(16)));
typedef float float4v   __attribute__((ext_vector_type(4)));

// async global->LDS, 16B/lane; dest = wave-uniform base + lane*16 (linear).
__device__ __forceinline__ void gll16(const void* g, void* l) {
    __builtin_amdgcn_global_load_lds(
        (const __attribute__((address_space(1))) void*)g,
        (__attribute__((address_space(3))) void*)l, 16, 0, 0);
}

// ---- K0: Q projection (pair-interleaved Qb rows: row 2i = Q1_i, 2i+1 = Q2_i) ----
__launch_bounds__(256, 4)
__global__ void k_q(const float* __restrict__ V, const float* __restrict__ W1,
                    const float* __restrict__ W2, _Float16* __restrict__ Qb) {
    int ib = blockIdx.x;
    int t  = threadIdx.x;
    bool isQ2 = ib >= 80;
    int i0l = (ib - (isQ2 ? 80 : 0)) * 4;
    __shared__ float inv4[4];
    float acc[4][4];
    #pragma unroll
    for (int ii = 0; ii < 4; ++ii)
        #pragma unroll
        for (int j = 0; j < 4; ++j) acc[ii][j] = 0.f;
    if (i0l < NA) {
        int row = t >> 6, l64 = t & 63;
        float s = 0.f;
        for (int v = l64; v < DV; v += 64) { float x = V[(i0l + row) * DV + v]; s += x * x; }
        #pragma unroll
        for (int o = 32; o; o >>= 1) s += __shfl_xor(s, o, 64);
        if (l64 == 0) inv4[row] = 1.f / fmaxf(sqrtf(s), 1e-12f);
        __syncthreads();
        const float* W  = isQ2 ? W2 : W1;
        const float* Vb = V + (size_t)i0l * DV;
        for (int v = 0; v < DV; v += 2) {
            float4v w0 = *(const float4v*)(W + (size_t)v * CF + t * 4);
            float4v w1 = *(const float4v*)(W + (size_t)(v + 1) * CF + t * 4);
            #pragma unroll
            for (int ii = 0; ii < 4; ++ii) {
                float a0 = Vb[(size_t)ii * DV + v];
                float a1 = Vb[(size_t)ii * DV + v + 1];
                #pragma unroll
                for (int j = 0; j < 4; ++j) acc[ii][j] += a0 * w0[j] + a1 * w1[j];
            }
        }
        #pragma unroll
        for (int ii = 0; ii < 4; ++ii)
            #pragma unroll
            for (int j = 0; j < 4; ++j) acc[ii][j] *= inv4[ii];
    }
    int fg = t >> 3;
    int fo = (t & 7) * 4;
    int q12 = isQ2 ? 1 : 0;
    #pragma unroll
    for (int ii = 0; ii < 4; ++ii) {
        half4 h;
        #pragma unroll
        for (int j = 0; j < 4; ++j) h[j] = (_Float16)acc[ii][j];
        *(half4*)&Qb[((size_t)fg * MT + (2 * (i0l + ii) + q12)) * 32 + fo] = h;
    }
}

// ---- K1: m97-geometry fused GEMM. block = (b, mt, nh): 128x128 tile,     ----
// ---- BK=32, 4 waves 2x2, acc[2][2]=64 AGPR, 2-phase loop, compiler waits ----
__launch_bounds__(256, 3)
__global__ void k_fused(const float* __restrict__ img, const _Float16* __restrict__ Qb,
                        float* __restrict__ pm, float* __restrict__ ps,
                        float* __restrict__ pd) {
    __shared__ __align__(16) char smem_s[2 * BUFSZ];

    int lin = blockIdx.x;          // 0..1279
    int b   = lin & 127;           // lin%8 = b%8 -> all 10 sub-blocks of b on one XCD
    int sub = lin >> 7;            // 0..9
    int mt  = sub >> 1;            // 0..4: Qb rows [mt*128, +128)
    int nh  = sub & 1;             // 0..1: img cols [nh*128, +128)

    int tid  = threadIdx.x;        // 0..255
    int lane = tid & 63;
    int w    = tid >> 6;           // 0..3
    int wr   = w >> 1;             // 0..1: rows [wr*64, +64)
    int wc   = w & 1;              // 0..1: cols [wc*64, +64)
    int nl   = lane & 31;
    int kh   = lane >> 5;

    // A staging: slot s = oct*128 + row (2 per thread); src (mt*128+row)*64 + oct*16
    int aG0, aG1;
    {
        int s0 = tid,        s1 = tid + 256;
        aG0 = (mt * 128 + (s0 & 127)) * 64 + (s0 >> 7) * 16;
        aG1 = (mt * 128 + (s1 & 127)) * 64 + (s1 >> 7) * 16;
    }
    const char* gA = (const char*)Qb;

    // B staging: thread owns r = tid&127, fg = tid>>7 (16 f = octets fg*2, fg*2+1)
    int rB = tid & 127, fg = tid >> 7;
    const float* gB = img + (size_t)b * CF * RR + (size_t)fg * 16 * RR
                      + nh * 128 + rB;

    float16v acc[2][2];
    #pragma unroll
    for (int i = 0; i < 2; ++i)
        #pragma unroll
        for (int j = 0; j < 2; ++j)
            #pragma unroll
            for (int gi = 0; gi < 16; ++gi) acc[i][j][gi] = 0.f;
    float ssq = 0.f;               // col rB, this thread's 16 f per kc
    float Bv[16];

    #define AGLL(kc_, bsel) do {                                                   \
        const char* aS = gA + (size_t)(kc_) * (MT * 64);                           \
        char* buf_ = smem_s + (int)(bsel) * BUFSZ;                                 \
        gll16(aS + aG0, buf_ + tid * 16);                                          \
        gll16(aS + aG1, buf_ + tid * 16 + 4096);                                   \
    } while (0)

    #define BLOAD(kc_) do {                                                        \
        const float* p = gB + (size_t)(kc_) * 32 * RR;                             \
        _Pragma("unroll")                                                          \
        for (int j = 0; j < 16; ++j) Bv[j] = p[(size_t)j * RR];                    \
    } while (0)

    // convert 16 f32 -> 2x half8, accumulate ssq, write B octets fg*2, fg*2+1
    #define CVTW(bsel) do {                                                        \
        half8 h0, h1;                                                              \
        _Pragma("unroll")                                                          \
        for (int j = 0; j < 8; ++j) {                                              \
            float x0 = Bv[j], x1 = Bv[8 + j];                                      \
            ssq += x0 * x0 + x1 * x1;                                              \
            h0[j] = (_Float16)x0; h1[j] = (_Float16)x1;                            \
        }                                                                          \
        char* bb = smem_s + (int)(bsel) * BUFSZ + 8192 + (fg * 2 * 128 + rB) * 16; \
        *(half8*)bb = h0;                                                          \
        *(half8*)(bb + 2048) = h1;                                                 \
    } while (0)

    #define COMPUTE(bsel) do {                                                     \
        const char* Al = smem_s + (int)(bsel) * BUFSZ;                             \
        const char* Bl = Al + 8192;                                                \
        _Pragma("unroll")                                                          \
        for (int ks = 0; ks < 2; ++ks) {                                           \
            int oct = ks * 2 + kh;                                                 \
            half8 bf0 = *(const half8*)(Bl + (oct * 128 + wc * 64 + nl) * 16);     \
            half8 bf1 = *(const half8*)(Bl + (oct * 128 + wc * 64 + 32 + nl) * 16);\
            half8 af0 = *(const half8*)(Al + (oct * 128 + wr * 64 + nl) * 16);     \
            half8 af1 = *(const half8*)(Al + (oct * 128 + wr * 64 + 32 + nl) * 16);\
            acc[0][0] = __builtin_amdgcn_mfma_f32_32x32x16_f16(af0, bf0, acc[0][0], 0, 0, 0); \
            acc[0][1] = __builtin_amdgcn_mfma_f32_32x32x16_f16(af0, bf1, acc[0][1], 0, 0, 0); \
            acc[1][0] = __builtin_amdgcn_mfma_f32_32x32x16_f16(af1, bf0, acc[1][0], 0, 0, 0); \
            acc[1][1] = __builtin_amdgcn_mfma_f32_32x32x16_f16(af1, bf1, acc[1][1], 0, 0, 0); \
        }                                                                          \
    } while (0)

    // prologue: build tile 0 in buf0
    BLOAD(0);
    CVTW(0);
    AGLL(0, 0);
    __syncthreads();

    #pragma unroll 1
    for (int kc = 0; kc < NKC - 1; ++kc) {
        BLOAD(kc + 1);                 // issue early; COMPUTE covers latency
        AGLL(kc + 1, (kc + 1) & 1);    // DMA into buffer released at kc-1's barrier
        COMPUTE(kc & 1);
        CVTW((kc + 1) & 1);            // waits Bv(kc+1); writes after compute
        __syncthreads();               // tile kc+1 complete; buf(kc) released
    }
    COMPUTE((NKC - 1) & 1);
    __syncthreads();

    #undef AGLL
    #undef BLOAD
    #undef CVTW
    #undef COMPUTE

    // ---- epilogue: col norms, softmax partials over this block's 128 cols ----
    float* ssq_lds = (float*)smem_s;              // [2][128]
    float* mred    = (float*)(smem_s + 1024);     // [2][64]
    float* mg      = (float*)(smem_s + 1536);     // [64]
    float* sred    = (float*)(smem_s + 1792);     // [2][64]
    float* dred    = (float*)(smem_s + 2304);     // [2][64]

    ssq_lds[fg * 128 + rB] = ssq;
    __syncthreads();
    int c0 = wc * 64 + nl;
    float iv0 = 1.f / fmaxf(sqrtf(ssq_lds[c0] + ssq_lds[128 + c0]), 1e-12f);
    float iv1 = 1.f / fmaxf(sqrtf(ssq_lds[c0 + 32] + ssq_lds[128 + c0 + 32]), 1e-12f);
    #pragma unroll
    for (int mi = 0; mi < 2; ++mi)
        #pragma unroll
        for (int gi = 0; gi < 16; ++gi) {
            acc[mi][0][gi] *= iv0;
            acc[mi][1][gi] *= iv1;
        }

    // pass 1: per-pair max over the block's 128 cols
    #pragma unroll
    for (int mi = 0; mi < 2; ++mi) {
        #pragma unroll
        for (int e = 0; e < 8; ++e) {
            int g = 2 * e;
            float mx = fmaxf(acc[mi][0][g], acc[mi][1][g]);
            #pragma unroll
            for (int off = 1; off <= 16; off <<= 1)
                mx = fmaxf(mx, __shfl_xor(mx, off, 64));
            if (nl == 0) {
                int p = (e & 1) + 4 * (e >> 1) + 2 * kh;       // pair 0..15 in frag
                mred[wc * 64 + wr * 32 + mi * 16 + p] = mx;
            }
        }
    }
    __syncthreads();
    if (tid < 64) mg[tid] = fmaxf(mred[tid], mred[64 + tid]);
    __syncthreads();

    // pass 2: exp-sum and weighted Q2 dot (local max)
    #pragma unroll
    for (int mi = 0; mi < 2; ++mi) {
        #pragma unroll
        for (int e = 0; e < 8; ++e) {
            int g = 2 * e;
            int p = (e & 1) + 4 * (e >> 1) + 2 * kh;
            int i = wr * 32 + mi * 16 + p;
            float m  = mg[i];
            float e0 = __expf(acc[mi][0][g] - m);
            float e1 = __expf(acc[mi][1][g] - m);
            float s = e0 + e1;
            float d = e0 * acc[mi][0][g + 1] + e1 * acc[mi][1][g + 1];
            #pragma unroll
            for (int off = 1; off <= 16; off <<= 1) {
                s += __shfl_xor(s, off, 64);
                d += __shfl_xor(d, off, 64);
            }
            if (nl == 0) {
                sred[wc * 64 + i] = s;
                dred[wc * 64 + i] = d;
            }
        }
    }
    __syncthreads();
    if (tid < 64) {
        size_t pb = ((size_t)b * 2 + nh) * NPI + mt * 64 + tid;
        pm[pb] = mg[tid];
        ps[pb] = sred[tid] + sred[64 + tid];
        pd[pb] = dred[tid] + dred[64 + tid];
    }
}

// ---- K2: combine the two col-halves (flash-style) ----
__launch_bounds__(256, 4)
__global__ void k_comb(const float* __restrict__ pm, const float* __restrict__ ps,
                       const float* __restrict__ pd, float* __restrict__ out) {
    int idx = blockIdx.x * 256 + threadIdx.x;   // 0..40959 = 128*320
    int b = idx / NPI;
    int i = idx - b * NPI;
    float m0 = pm[(size_t)(b * 2) * NPI + i];
    float m1 = pm[(size_t)(b * 2 + 1) * NPI + i];
    float m  = fmaxf(m0, m1);
    float w0 = __expf(m0 - m), w1 = __expf(m1 - m);
    float s = ps[(size_t)(b * 2) * NPI + i] * w0 + ps[(size_t)(b * 2 + 1) * NPI + i] * w1;
    float d = pd[(size_t)(b * 2) * NPI + i] * w0 + pd[(size_t)(b * 2 + 1) * NPI + i] * w1;
    if (i < NA) out[(size_t)b * NA + i] = d / s;
}

// ---- launcher ----
extern "C" void kernel_launch(void* const* d_in, const int* in_sizes, int n_in,
                              void* d_out, int out_size, void* d_ws, size_t ws_size,
                              hipStream_t stream) {
    const float* img = (const float*)d_in[0];
    const float* V   = (const float*)d_in[1];
    const float* W1  = (const float*)d_in[2];
    const float* W2  = (const float*)d_in[3];
    float* out = (float*)d_out;

    char* ws = (char*)d_ws;
    size_t off = 0;
    _Float16* Qb = (_Float16*)(ws + off); off += (size_t)NKC * MT * 32 * 2;
    float*    pm = (float*)(ws + off);    off += (size_t)NB * 2 * NPI * 4;
    float*    ps = (float*)(ws + off);    off += (size_t)NB * 2 * NPI * 4;
    float*    pd = (float*)(ws + off);    off += (size_t)NB * 2 * NPI * 4;

    k_q<<<dim3(NQ), 256, 0, stream>>>(V, W1, W2, Qb);
    k_fused<<<dim3(1280), 256, 0, stream>>>(img, Qb, pm, ps, pd);
    k_comb<<<dim3(160), 256, 0, stream>>>(pm, ps, pd, out);
}